// Round 6
// baseline (94.468 us; speedup 1.0000x reference)
//
#include <hip/hip_runtime.h>

// Fused 3D SSIM, window 7^3, VALID. pred/targ: (4,1,32,320,320) f32.
// Tile = 16h x 32w outputs, 2 adjacent w-outputs per thread; t split in 2
// halves (13 outputs each, 19 slices). One barrier per slice, double-buffered
// sp/sq + transposed col. 4 tracked fields: f0=sum p, f1=sum q,
// f2=sum p^2+q^2, f3=sum p*q.
// Per slice: commit staged slice s+1 | row-paired column sums of slice s
// (written as float2 row-pairs into col-major colT) | prefetch s+2 ->
// barrier -> rowgather (7 singles + 1 extra for the odd output) + ring.

#define WIN 7
#define NPIX 343

constexpr int B = 4, T = 32, H = 320, W = 320;
constexpr int TO = T - 6, HO = H - 6, WO = W - 6;   // 26, 314, 314
constexpr long long NOUT = (long long)B * TO * HO * WO;

constexpr int TH = 16, TW = 32;      // output tile
constexpr int IH = 22;               // input tile rows (+6 halo)
constexpr int SPW = 44;              // sp/sq row stride (16B-aligned rows)
constexpr int NCOL = 38;             // columns of col sums (0..37)
constexpr int CRW  = 18;             // colT inner (row) stride
constexpr int NTH = 20, NTW = 10;
constexpr int OT_PER = 13, NS = OT_PER + 6;  // 19 slices per half

__global__ __launch_bounds__(256) void ssim3d_fused(
    const float* __restrict__ pred,
    const float* __restrict__ targ,
    const float* __restrict__ drange,
    double* __restrict__ acc)
{
    __shared__ float sp[2][IH][SPW];
    __shared__ float sq[2][IH][SPW];
    __shared__ float colT[2][4][NCOL][CRW];   // [buf][field][col][row]
    __shared__ float wsum[4];

    const int bx   = blockIdx.x;
    const int b    = bx / (2 * NTH * NTW);
    int rem        = bx % (2 * NTH * NTW);
    const int half = rem / (NTH * NTW);
    rem            = rem % (NTH * NTW);
    const int h0   = (rem / NTW) * TH;
    const int w0   = (rem % NTW) * TW;
    const int t0   = half * OT_PER;

    const int tid = threadIdx.x;

    const float* pb = pred + (long long)b * T * H * W;
    const float* qb = targ + (long long)b * T * H * W;

    // ---- staging: 440 float4 items = 2 fields x 22 rows x 10 f4-cols ----
    const int f0s = tid / 220, rm0 = tid % 220;
    const int r0s = rm0 / 10, c0s = rm0 % 10;
    const int gr0 = min(h0 + r0s, H - 1), gc0 = min(w0 + 4 * c0s, W - 4);
    const float* gb0 = (f0s ? qb : pb) + (long long)gr0 * W + gc0;
    const int o0 = r0s * SPW + 4 * c0s;

    const bool act1 = (tid < 184);
    const int item1 = 256 + tid;
    const int f1s = item1 / 220, rm1 = item1 % 220;
    const int r1s = rm1 / 10, c1s = rm1 % 10;
    const int gr1 = min(h0 + r1s, H - 1), gc1 = min(w0 + 4 * c1s, W - 4);
    const float* gb1 = (f1s ? qb : pb) + (long long)gr1 * W + gc1;
    const int o1 = r1s * SPW + 4 * c1s;

    float4 pr0, pr1;
    auto prefetchw = [&](int s) {
        const long long so = (long long)(t0 + s) * H * W;
        pr0 = *reinterpret_cast<const float4*>(gb0 + so);
        if (act1) pr1 = *reinterpret_cast<const float4*>(gb1 + so);
    };
    auto commitw = [&](int buf) {
        float* d0 = (f0s ? &sq[buf][0][0] : &sp[buf][0][0]) + o0;
        *reinterpret_cast<float4*>(d0) = pr0;
        if (act1) {
            float* d1 = (f1s ? &sq[buf][0][0] : &sp[buf][0][0]) + o1;
            *reinterpret_cast<float4*>(d1) = pr1;
        }
    };

    // ---- colsum mapping: 152 items = 8 row-pairs x 19 col-pairs ----
    // rp in low bits so a wave's 8 rps x 8 cpis spread bank bases.
    const bool colw = (tid < 152);
    const int rp  = tid & 7;          // row-pair 0..7
    const int cpi = tid >> 3;         // col-pair 0..18
    const int cr0 = 2 * rp;
    const int cc  = 2 * cpi;

    // ---- rowgather mapping: outputs (oh, 2k) and (oh, 2k+1) ----
    const int oh = tid >> 4, k = tid & 15;
    const bool vh = (h0 + oh < HO);
    const bool vE = vh && (w0 + 2 * k     < WO);
    const bool vO = vh && (w0 + 2 * k + 1 < WO);

    const float dr  = drange[b];
    const float C1v = (0.01f * dr) * (0.01f * dr);
    const float C2v = (0.03f * dr) * (0.03f * dr);
    const float inv  = 1.0f / (float)NPIX;
    const float covn = (float)NPIX / (float)(NPIX - 1);

    float rE[4][7], rO[4][7], tE[4], tO[4];
#pragma unroll
    for (int f = 0; f < 4; ++f) {
        tE[f] = tO[f] = 0.f;
#pragma unroll
        for (int j = 0; j < 7; ++j) { rE[f][j] = rO[f][j] = 0.f; }
    }
    float loss = 0.f;

    auto ssim1 = [&](const float* tt) {
        float ux  = tt[0] * inv, uy = tt[1] * inv;
        float u2  = tt[2] * inv, uxy = tt[3] * inv;
        float B2 = covn * (u2 - ux * ux - uy * uy) + C2v;
        float A2 = 2.f * covn * (uxy - ux * uy) + C2v;
        float A1 = 2.f * ux * uy + C1v;
        float B1 = ux * ux + uy * uy + C1v;
        return 1.f - __fdividef(A1 * A2, B1 * B2);
    };

    // ---- prologue ----
    prefetchw(0);
    commitw(0);
    prefetchw(1);
    __syncthreads();

    for (int a = 0; a < 21; a += 7) {
#pragma unroll
        for (int jj = 0; jj < 7; ++jj) {
            const int s = a + jj;
            if (s < NS) {
                const int bs = s & 1, bn = bs ^ 1;

                if (s + 1 < NS) commitw(bn);

                if (colw) {
                    float2 mid[4], row0[4], row7[4];
#pragma unroll
                    for (int dy = 0; dy < 8; ++dy) {
                        float2 p = *reinterpret_cast<const float2*>(&sp[bs][cr0 + dy][cc]);
                        float2 q = *reinterpret_cast<const float2*>(&sq[bs][cr0 + dy][cc]);
                        float2 v[4];
                        v[0] = p;
                        v[1] = q;
                        v[2] = make_float2(fmaf(p.x, p.x, q.x * q.x),
                                           fmaf(p.y, p.y, q.y * q.y));
                        v[3] = make_float2(p.x * q.x, p.y * q.y);
                        if (dy == 0) {
#pragma unroll
                            for (int f = 0; f < 4; ++f) row0[f] = v[f];
                        } else if (dy == 7) {
#pragma unroll
                            for (int f = 0; f < 4; ++f) row7[f] = v[f];
                        } else if (dy == 1) {
#pragma unroll
                            for (int f = 0; f < 4; ++f) mid[f] = v[f];
                        } else {
#pragma unroll
                            for (int f = 0; f < 4; ++f) {
                                mid[f].x += v[f].x; mid[f].y += v[f].y;
                            }
                        }
                    }
#pragma unroll
                    for (int f = 0; f < 4; ++f) {
                        float ax  = row0[f].x + mid[f].x;   // (row cr0,   col cc)
                        float ay  = row0[f].y + mid[f].y;   // (row cr0,   col cc+1)
                        float bxv = mid[f].x + row7[f].x;   // (row cr0+1, col cc)
                        float byv = mid[f].y + row7[f].y;   // (row cr0+1, col cc+1)
                        // col-major: rows contiguous -> row-pair as one float2
                        *reinterpret_cast<float2*>(&colT[bs][f][cc][cr0])     = make_float2(ax, bxv);
                        *reinterpret_cast<float2*>(&colT[bs][f][cc + 1][cr0]) = make_float2(ay, byv);
                    }
                }

                if (s + 2 < NS) prefetchw(s + 2);

                __syncthreads();   // colT[bs] ready; sp[bn] committed

                // ---- rowgather: S7 even = cols 2k..2k+6; odd adds col 2k+7, drops 2k
                float sEv[4], sOv[4];
#pragma unroll
                for (int f = 0; f < 4; ++f) {
                    const float* cf = &colT[bs][f][0][0] + 2 * k * CRW + oh;
                    float c0 = cf[0];
                    float s7 = c0 + cf[CRW] + cf[2*CRW] + cf[3*CRW]
                                  + cf[4*CRW] + cf[5*CRW] + cf[6*CRW];
                    sEv[f] = s7;
                    sOv[f] = s7 - c0 + cf[7*CRW];
                }
#pragma unroll
                for (int f = 0; f < 4; ++f) {
                    tE[f] += sEv[f] - rE[f][jj];  rE[f][jj] = sEv[f];
                    tO[f] += sOv[f] - rO[f][jj];  rO[f][jj] = sOv[f];
                }

                if (s >= 6) {
                    if (vE) loss += ssim1(tE);
                    if (vO) loss += ssim1(tO);
                }
            }
        }
    }

    // ---- block reduction -> global atomic ----
    for (int off = 32; off > 0; off >>= 1)
        loss += __shfl_down(loss, off, 64);
    const int lane = tid & 63;
    const int wid  = tid >> 6;
    if (lane == 0) wsum[wid] = loss;
    __syncthreads();
    if (tid == 0) {
        float s = wsum[0] + wsum[1] + wsum[2] + wsum[3];
        atomicAdd(acc, (double)s);
    }
}

__global__ void ssim3d_finalize(const double* __restrict__ acc,
                                float* __restrict__ out)
{
    out[0] = (float)(acc[0] / (double)NOUT);
}

extern "C" void kernel_launch(void* const* d_in, const int* in_sizes, int n_in,
                              void* d_out, int out_size, void* d_ws, size_t ws_size,
                              hipStream_t stream)
{
    const float* pred   = (const float*)d_in[0];
    const float* targ   = (const float*)d_in[1];
    const float* drange = (const float*)d_in[2];
    float* out  = (float*)d_out;
    double* acc = (double*)d_ws;

    hipMemsetAsync(acc, 0, sizeof(double), stream);

    const int nblocks = B * 2 * NTH * NTW;  // 1600
    ssim3d_fused<<<nblocks, 256, 0, stream>>>(pred, targ, drange, acc);
    ssim3d_finalize<<<1, 1, 0, stream>>>(acc, out);
}